// Round 14
// baseline (683.864 us; speedup 1.0000x reference)
//
#include <hip/hip_runtime.h>
#include <hip/hip_bf16.h>

typedef unsigned short u16;
typedef u16   u16x4 __attribute__((ext_vector_type(4)));
typedef u16   u16x8 __attribute__((ext_vector_type(8)));
typedef short bf16x8 __attribute__((ext_vector_type(8)));
typedef float f32x4 __attribute__((ext_vector_type(4)));

#define R_    128
#define L_    512
#define E_    768
#define H_    12
#define RD_   8192        // R_ * 64
#define M_    65536       // R_ * L_
#define OUT0_N 50331648   // M_ * E_
#define PART_ 3145728     // 12*512*512 (one logits partial, fp32 elems)

// round-to-nearest-even fp32 -> bf16 (data has no NaN/Inf)
__device__ __forceinline__ u16 rne_bf16(float f) {
  unsigned u = __builtin_bit_cast(unsigned, f);
  u += 0x7FFFu + ((u >> 16) & 1u);
  return (u16)(u >> 16);
}

// pack two fp32 -> u32 of 2 bf16 (RNE, identical numerics to rne_bf16 path)
__device__ __forceinline__ unsigned pack2(float a, float b) {
  return (unsigned)rne_bf16(a) | ((unsigned)rne_bf16(b) << 16);
}

// non-temporal store: keep streaming outputs from evicting the L2 operand
// window (R13: confirmed -20us). Full-line no-reuse streams only.
template <typename T>
__device__ __forceinline__ void nt_store(T* p, T v) {
  __builtin_nontemporal_store(v, p);
}

// async global->LDS, 16 B per lane (global_load_lds_dwordx4)
__device__ __forceinline__ void gload_lds16(const u16* g, u16* l) {
  __builtin_amdgcn_global_load_lds(
      (const __attribute__((address_space(1))) void*)g,
      (__attribute__((address_space(3))) void*)l, 16, 0, 0);
}

// bijective XCD-aware remap (nwg % 8 == 0): contiguous logical chunk per XCD
__device__ __forceinline__ int xcd_remap(int d, int nwg) {
  return (d & 7) * (nwg >> 3) + (d >> 3);
}

// ===========================================================================
// 256x256-tile NT GEMM core with FP32 A (fused convert): C += cvt(Af)*B^T.
// R14 change: A is read directly from fp32 x (reg-staged, rne-converted,
// ds_write_b64 into the SAME swizzled LDS layout the reads expect) --
// eliminates the standalone 300-MB x->bf16 conversion pass. B unchanged
// (global_load_lds). 512 thr = 8 waves (2Mx4N), wave tile 128x64, BK=64,
// LDS = 2 buf x (A[256][64]+B[256][64]) = 128 KB.
// Per-tile schedule (4 phases, each: {ds_read || stage} -> bar -> 16 MFMA):
//   p0: ds_read bff/af(rd0,a0-3) ; issue A-loads q0-3 of t+1
//   p1: ds_read af(rd0,a4-7)     ; cvt+write q0-3 ; issue A-loads q4-7
//   p2: ds_read bff/af(rd1,a0-3) ; gload B0-3 of t+1 ; cvt+write q4-7
//   p3: ds_read af(rd1,a4-7)     ; end: vmcnt(0)+lgkmcnt(0) -> barrier
// Ledger: A-loads have >=1 phase (~1600cyc) of slack before cvt (compiler
// auto-waits on register deps); B gloads issued p2, drained at tile end
// (~1.5 phases, L2-resident weights). bufn's last reader was tile t-1
// (barrier-separated); lgkmcnt(0) before the tile-end barrier makes the
// ds_writes visible to all waves before t+1's reads.
// Swizzle (both-sides, rule #21): L[row][s] = G[row][s ^ (row&7)]; A write
// side computes the XOR explicitly, B write side pre-swizzles the global
// source slot; read slot = (kk*4+(lane>>4)) ^ (lane&7). Read side identical
// to R8/R13 (proven).
// ===========================================================================
__device__ __forceinline__ void gemm_core256_f32a(
    const float* __restrict__ Af, const u16* __restrict__ Bb,
    const int lda_f, const int ldb, const int K,
    u16* sm, f32x4 acc[8][4])
{
  const int t    = threadIdx.x;          // 0..511
  const int lane = t & 63;
  const int w    = t >> 6;               // 0..7
  const int wm   = (w >> 2) << 7;        // 0 | 128
  const int wn   = (w & 3) << 6;         // 0..192
  const int frow = lane & 15;

  // B staging: one gload covers 64 rows x 128 B (512 thr x 16 B)
  const int crow  = t >> 3;
  const int gslot = (t & 7) ^ (crow & 7);          // pre-swizzled source slot
  const u16* gB = Bb + (size_t)crow * ldb + (gslot << 3);
  const int stg = t << 3;                          // linear LDS dest (elems)

  // A fp32 staging: pass q covers rows [q*32, q*32+32) x 64 k-cols.
  // thread t -> row q*32+(t>>4), fp32 cols (t&15)*4..+4 (1 KB/instr coalesced)
  const int arow = t >> 4;                         // 0..31 (row&7 == arow&7)
  const float* gA = Af + (size_t)arow * lda_f + ((t & 15) << 2);
  const int s_log = (t & 15) >> 1;                 // logical 16B slot
  const int aswz  = ((s_log ^ (arow & 7)) << 3) + ((t & 1) << 2);  // u16 elems

  // swizzled read slots (8 slots/row of 128 B)
  const int rd0 = (((lane >> 4)    ) ^ (lane & 7)) << 3;
  const int rd1 = (((lane >> 4) | 4) ^ (lane & 7)) << 3;

#define LD_A(q_, ko_) (*(const float4*)(gA + (size_t)((q_) << 5) * lda_f + (ko_)))
#define WR_A(q_, f_, buf_)                                               \
  {                                                                      \
    uint2 pk_;                                                           \
    pk_.x = pack2((f_).x, (f_).y);                                       \
    pk_.y = pack2((f_).z, (f_).w);                                       \
    *(uint2*)((buf_) + ((((q_) << 5) + arow) << 6) + aswz) = pk_;        \
  }
#define STG_B(c_, buf_, ko_) \
  gload_lds16(gB + (ko_) + (size_t)((c_) << 6) * ldb, (buf_) + 16384 + ((c_) << 12) + stg)

  const int nt = K >> 6;
  // prologue: tile 0 staged and landed
  {
    float4 fa0 = LD_A(0, 0), fa1 = LD_A(1, 0), fa2 = LD_A(2, 0), fa3 = LD_A(3, 0);
    float4 fb0 = LD_A(4, 0), fb1 = LD_A(5, 0), fb2 = LD_A(6, 0), fb3 = LD_A(7, 0);
    STG_B(0, sm, 0); STG_B(1, sm, 0); STG_B(2, sm, 0); STG_B(3, sm, 0);
    WR_A(0, fa0, sm); WR_A(1, fa1, sm); WR_A(2, fa2, sm); WR_A(3, fa3, sm);
    WR_A(4, fb0, sm); WR_A(5, fb1, sm); WR_A(6, fb2, sm); WR_A(7, fb3, sm);
    asm volatile("s_waitcnt vmcnt(0) lgkmcnt(0)" ::: "memory");
    __builtin_amdgcn_s_barrier();
  }

  for (int tt = 0; tt < nt; ++tt) {
    u16* bufc = sm + ((tt & 1) << 15);
    u16* bufn = sm + (((tt + 1) & 1) << 15);
    const bool st = (tt + 1 < nt);
    const int ko = (tt + 1) << 6;       // col offset: fp32 for A, bf16 for B

    bf16x8 af[4], bff[4];
    float4 fa0, fa1, fa2, fa3, fb0, fb1, fb2, fb3;

    // ---------- phase 0: kk=0, a=0..3 ; issue A q0-3 of t+1 ----------
#pragma unroll
    for (int b = 0; b < 4; ++b)
      bff[b] = *(const bf16x8*)(bufc + 16384 + ((wn + b * 16 + frow) << 6) + rd0);
#pragma unroll
    for (int a = 0; a < 4; ++a)
      af[a] = *(const bf16x8*)(bufc + ((wm + a * 16 + frow) << 6) + rd0);
    if (st) { fa0 = LD_A(0, ko); fa1 = LD_A(1, ko); fa2 = LD_A(2, ko); fa3 = LD_A(3, ko); }
    __builtin_amdgcn_s_barrier();
    __builtin_amdgcn_s_setprio(1);
#pragma unroll
    for (int a = 0; a < 4; ++a)
#pragma unroll
      for (int b = 0; b < 4; ++b)
        acc[a][b] = __builtin_amdgcn_mfma_f32_16x16x32_bf16(af[a], bff[b], acc[a][b], 0, 0, 0);
    __builtin_amdgcn_s_setprio(0);
    __builtin_amdgcn_s_barrier();

    // ---------- phase 1: kk=0, a=4..7 ; cvt+write q0-3 ; issue A q4-7 ----------
#pragma unroll
    for (int a = 0; a < 4; ++a)
      af[a] = *(const bf16x8*)(bufc + ((wm + (a + 4) * 16 + frow) << 6) + rd0);
    if (st) {
      fb0 = LD_A(4, ko); fb1 = LD_A(5, ko); fb2 = LD_A(6, ko); fb3 = LD_A(7, ko);
      WR_A(0, fa0, bufn); WR_A(1, fa1, bufn); WR_A(2, fa2, bufn); WR_A(3, fa3, bufn);
    }
    __builtin_amdgcn_s_barrier();
    __builtin_amdgcn_s_setprio(1);
#pragma unroll
    for (int a = 0; a < 4; ++a)
#pragma unroll
      for (int b = 0; b < 4; ++b)
        acc[a + 4][b] = __builtin_amdgcn_mfma_f32_16x16x32_bf16(af[a], bff[b], acc[a + 4][b], 0, 0, 0);
    __builtin_amdgcn_s_setprio(0);
    __builtin_amdgcn_s_barrier();

    // ---------- phase 2: kk=1, a=0..3 ; gload B0-3 ; cvt+write q4-7 ----------
#pragma unroll
    for (int b = 0; b < 4; ++b)
      bff[b] = *(const bf16x8*)(bufc + 16384 + ((wn + b * 16 + frow) << 6) + rd1);
#pragma unroll
    for (int a = 0; a < 4; ++a)
      af[a] = *(const bf16x8*)(bufc + ((wm + a * 16 + frow) << 6) + rd1);
    if (st) {
      STG_B(0, bufn, ko); STG_B(1, bufn, ko); STG_B(2, bufn, ko); STG_B(3, bufn, ko);
      WR_A(4, fb0, bufn); WR_A(5, fb1, bufn); WR_A(6, fb2, bufn); WR_A(7, fb3, bufn);
    }
    __builtin_amdgcn_s_barrier();
    __builtin_amdgcn_s_setprio(1);
#pragma unroll
    for (int a = 0; a < 4; ++a)
#pragma unroll
      for (int b = 0; b < 4; ++b)
        acc[a][b] = __builtin_amdgcn_mfma_f32_16x16x32_bf16(af[a], bff[b], acc[a][b], 0, 0, 0);
    __builtin_amdgcn_s_setprio(0);
    __builtin_amdgcn_s_barrier();

    // ---------- phase 3: kk=1, a=4..7 ----------
#pragma unroll
    for (int a = 0; a < 4; ++a)
      af[a] = *(const bf16x8*)(bufc + ((wm + (a + 4) * 16 + frow) << 6) + rd1);
    __builtin_amdgcn_s_barrier();
    __builtin_amdgcn_s_setprio(1);
#pragma unroll
    for (int a = 0; a < 4; ++a)
#pragma unroll
      for (int b = 0; b < 4; ++b)
        acc[a + 4][b] = __builtin_amdgcn_mfma_f32_16x16x32_bf16(af[a], bff[b], acc[a + 4][b], 0, 0, 0);
    __builtin_amdgcn_s_setprio(0);
    asm volatile("s_waitcnt vmcnt(0) lgkmcnt(0)" ::: "memory");  // B landed; A-writes visible
    __builtin_amdgcn_s_barrier();
  }
#undef LD_A
#undef WR_A
#undef STG_B
}

// ===========================================================================
// 256x256-tile NT GEMM core, bf16 A+B (R8/R13 proven) -- used by ctx/out.
// ===========================================================================
__device__ __forceinline__ void gemm_core256(
    const u16* __restrict__ Ab, const u16* __restrict__ Bb,
    const int lda, const int ldb, const int K,
    u16* sm, f32x4 acc[8][4])
{
  const int t    = threadIdx.x;          // 0..511
  const int lane = t & 63;
  const int w    = t >> 6;               // 0..7
  const int wm   = (w >> 2) << 7;        // 0 | 128
  const int wn   = (w & 3) << 6;         // 0..192
  const int frow = lane & 15;

  const int crow  = t >> 3;
  const int gslot = (t & 7) ^ (crow & 7);
  const u16* gA = Ab + (size_t)crow * lda + (gslot << 3);
  const u16* gB = Bb + (size_t)crow * ldb + (gslot << 3);
  const int stg = t << 3;

  const int rd0 = (((lane >> 4)    ) ^ (lane & 7)) << 3;
  const int rd1 = (((lane >> 4) | 4) ^ (lane & 7)) << 3;

#define STG_A(c_, buf_, ko_) \
  gload_lds16(gA + (ko_) + (size_t)((c_) << 6) * lda, (buf_) + ((c_) << 12) + stg)
#define STG_B(c_, buf_, ko_) \
  gload_lds16(gB + (ko_) + (size_t)((c_) << 6) * ldb, (buf_) + 16384 + ((c_) << 12) + stg)

  const int nt = K >> 6;
  STG_B(0, sm, 0); STG_B(1, sm, 0); STG_B(2, sm, 0); STG_B(3, sm, 0);
  STG_A(0, sm, 0); STG_A(2, sm, 0); STG_A(1, sm, 0); STG_A(3, sm, 0);
  asm volatile("s_waitcnt vmcnt(2)" ::: "memory");
  __builtin_amdgcn_s_barrier();

  for (int tt = 0; tt < nt; ++tt) {
    u16* bufc = sm + ((tt & 1) << 15);
    u16* bufn = sm + (((tt + 1) & 1) << 15);
    const bool st = (tt + 1 < nt);
    const int ko = (tt + 1) << 6;

    bf16x8 af[4], bff[4];
    // phase 0
#pragma unroll
    for (int b = 0; b < 4; ++b)
      bff[b] = *(const bf16x8*)(bufc + 16384 + ((wn + b * 16 + frow) << 6) + rd0);
#pragma unroll
    for (int a = 0; a < 4; ++a)
      af[a] = *(const bf16x8*)(bufc + ((wm + a * 16 + frow) << 6) + rd0);
    if (st) { STG_B(0, bufn, ko); STG_B(1, bufn, ko); }
    __builtin_amdgcn_s_barrier();
    __builtin_amdgcn_s_setprio(1);
#pragma unroll
    for (int a = 0; a < 4; ++a)
#pragma unroll
      for (int b = 0; b < 4; ++b)
        acc[a][b] = __builtin_amdgcn_mfma_f32_16x16x32_bf16(af[a], bff[b], acc[a][b], 0, 0, 0);
    __builtin_amdgcn_s_setprio(0);
    if (st) asm volatile("s_waitcnt vmcnt(2)" ::: "memory");
    else    asm volatile("s_waitcnt vmcnt(0)" ::: "memory");
    __builtin_amdgcn_s_barrier();

    // phase 1
#pragma unroll
    for (int a = 0; a < 4; ++a)
      af[a] = *(const bf16x8*)(bufc + ((wm + (a + 4) * 16 + frow) << 6) + rd0);
    if (st) { STG_B(2, bufn, ko); STG_B(3, bufn, ko); }
    __builtin_amdgcn_s_barrier();
    __builtin_amdgcn_s_setprio(1);
#pragma unroll
    for (int a = 0; a < 4; ++a)
#pragma unroll
      for (int b = 0; b < 4; ++b)
        acc[a + 4][b] = __builtin_amdgcn_mfma_f32_16x16x32_bf16(af[a], bff[b], acc[a + 4][b], 0, 0, 0);
    __builtin_amdgcn_s_setprio(0);
    __builtin_amdgcn_s_barrier();

    // phase 2
#pragma unroll
    for (int b = 0; b < 4; ++b)
      bff[b] = *(const bf16x8*)(bufc + 16384 + ((wn + b * 16 + frow) << 6) + rd1);
#pragma unroll
    for (int a = 0; a < 4; ++a)
      af[a] = *(const bf16x8*)(bufc + ((wm + a * 16 + frow) << 6) + rd1);
    if (st) { STG_A(0, bufn, ko); STG_A(2, bufn, ko); }
    __builtin_amdgcn_s_barrier();
    __builtin_amdgcn_s_setprio(1);
#pragma unroll
    for (int a = 0; a < 4; ++a)
#pragma unroll
      for (int b = 0; b < 4; ++b)
        acc[a][b] = __builtin_amdgcn_mfma_f32_16x16x32_bf16(af[a], bff[b], acc[a][b], 0, 0, 0);
    __builtin_amdgcn_s_setprio(0);
    __builtin_amdgcn_s_barrier();

    // phase 3
#pragma unroll
    for (int a = 0; a < 4; ++a)
      af[a] = *(const bf16x8*)(bufc + ((wm + (a + 4) * 16 + frow) << 6) + rd1);
    if (st) { STG_A(1, bufn, ko); STG_A(3, bufn, ko); }
    __builtin_amdgcn_s_barrier();
    __builtin_amdgcn_s_setprio(1);
#pragma unroll
    for (int a = 0; a < 4; ++a)
#pragma unroll
      for (int b = 0; b < 4; ++b)
        acc[a + 4][b] = __builtin_amdgcn_mfma_f32_16x16x32_bf16(af[a], bff[b], acc[a + 4][b], 0, 0, 0);
    __builtin_amdgcn_s_setprio(0);
    if (st) asm volatile("s_waitcnt vmcnt(2)" ::: "memory");
    __builtin_amdgcn_s_barrier();
  }
#undef STG_A
#undef STG_B
}

#define EPILOGUE_IDX256                           \
  const int lane = threadIdx.x & 63;              \
  const int w    = threadIdx.x >> 6;              \
  const int wm   = (w >> 2) << 7;                 \
  const int wn   = (w & 3) << 6;                  \
  const int row4 = (lane >> 4) << 2;              \
  const int coll = lane & 15;

#define ACC_INIT256                               \
  f32x4 acc[8][4];                                \
  {                                               \
    f32x4 zz = {0.0f, 0.0f, 0.0f, 0.0f};          \
    _Pragma("unroll")                             \
    for (int a = 0; a < 8; ++a)                   \
      _Pragma("unroll")                           \
      for (int b = 0; b < 4; ++b) acc[a][b] = zz; \
  }

// ===========================================================================
// 128x128-tile core (proven rounds 2-4) -- kept for k_gemm_logits.
// ===========================================================================
__device__ __forceinline__ void gemm_core(
    const u16* __restrict__ Ab, const u16* __restrict__ Bb,
    const int lda, const int ldb, const int K,
    u16* sm, f32x4 acc[4][4])
{
  const int t    = threadIdx.x;
  const int lane = t & 63;
  const int w    = t >> 6;
  const int wm   = (w >> 1) << 6;
  const int wn   = (w & 1) << 6;
  const int frow = lane & 15;

  const int srow = (w << 3) + (lane >> 3);
  const int scol = ((lane & 7) ^ (lane >> 3)) << 3;   // swizzled global col
  const u16* gA = Ab + (size_t)srow * lda + scol;
  const u16* gB = Bb + (size_t)srow * ldb + scol;
  const int stg_l = (w << 9) + (lane << 3);           // linear LDS dest

#pragma unroll
  for (int j = 0; j < 4; ++j) {
    gload_lds16(gA + (size_t)(j << 5) * lda, sm + (j << 11) + stg_l);
    gload_lds16(gB + (size_t)(j << 5) * ldb, sm + 8192 + (j << 11) + stg_l);
  }

  const int nt = K >> 6;
  for (int tt = 0; tt < nt; ++tt) {
    const int cur = tt & 1;
    u16* bufc = sm + (cur << 14);
    u16* bufn = sm + ((cur ^ 1) << 14);
    __builtin_amdgcn_s_barrier();
    if (tt + 1 < nt) {
      const u16* gA1 = gA + ((size_t)(tt + 1) << 6);
      const u16* gB1 = gB + ((size_t)(tt + 1) << 6);
#pragma unroll
      for (int j = 0; j < 4; ++j) {
        gload_lds16(gA1 + (size_t)(j << 5) * lda, bufn + (j << 11) + stg_l);
        gload_lds16(gB1 + (size_t)(j << 5) * ldb, bufn + 8192 + (j << 11) + stg_l);
      }
      asm volatile("s_waitcnt vmcnt(8)" ::: "memory");
    } else {
      asm volatile("s_waitcnt vmcnt(0)" ::: "memory");
    }
    __builtin_amdgcn_s_barrier();
    const u16* sA = bufc;
    const u16* sB = bufc + 8192;
#pragma unroll
    for (int kk = 0; kk < 2; ++kk) {
      const int rdcol = (((kk << 2) + (lane >> 4)) ^ (lane & 7)) << 3;
      bf16x8 af[4], bff[4];
#pragma unroll
      for (int a = 0; a < 4; ++a)
        af[a] = *(const bf16x8*)(sA + ((wm + a * 16 + frow) << 6) + rdcol);
#pragma unroll
      for (int b = 0; b < 4; ++b)
        bff[b] = *(const bf16x8*)(sB + ((wn + b * 16 + frow) << 6) + rdcol);
#pragma unroll
      for (int a = 0; a < 4; ++a)
#pragma unroll
        for (int b = 0; b < 4; ++b)
          acc[a][b] = __builtin_amdgcn_mfma_f32_16x16x32_bf16(af[a], bff[b], acc[a][b], 0, 0, 0);
    }
  }
}

#define EPILOGUE_IDX                              \
  const int lane = threadIdx.x & 63;              \
  const int w    = threadIdx.x >> 6;              \
  const int wm   = (w >> 1) << 6;                 \
  const int wn   = (w & 1) << 6;                  \
  const int row4 = (lane >> 4) << 2;              \
  const int coll = lane & 15;

#define ACC_INIT                                  \
  f32x4 acc[4][4];                                \
  {                                               \
    f32x4 zz = {0.0f, 0.0f, 0.0f, 0.0f};          \
    _Pragma("unroll")                             \
    for (int a = 0; a < 4; ++a)                   \
      _Pragma("unroll")                           \
      for (int b = 0; b < 4; ++b) acc[a][b] = zz; \
  }

// ---------------------------------------------------------------------------
// QKV projection (fp32-A fused-cvt 256sq core): x[65536x768] fp32 read
// directly; @ wqkv[2304x768]^T (+bias). q,k -> [h][i][r*64+d]; v ->
// transposed [h][r*64+d][j] via 4-pass LDS Tr. grid (9, 256) x 512 thr.
// __launch_bounds__(512,2): pin 2 waves/SIMD so the +fp32-staging VGPRs
// spill rather than halving occupancy.
// ---------------------------------------------------------------------------
__global__ __launch_bounds__(512, 2) void k_gemm_qkv(
    const float* __restrict__ xf, const u16* __restrict__ wqkv,
    const float* __restrict__ bq, const float* __restrict__ bk,
    const float* __restrict__ bv,
    u16* __restrict__ qt, u16* __restrict__ kt, u16* __restrict__ vt2,
    const float scaling)
{
  __shared__ __align__(16) u16 smem[65536];   // 128 KB: 2 x (A 32K | B 32K)
  const int d0 = blockIdx.x + 9 * blockIdx.y;
  const int l  = xcd_remap(d0, 2304);
  const int bn = l % 9;
  const int bm = l / 9;
  ACC_INIT256;
  gemm_core256_f32a(xf + (size_t)bm * 256 * E_, wqkv + (size_t)bn * 256 * E_,
                    E_, E_, E_, smem, acc);
  EPILOGUE_IDX256;
  const int which = bn / 3;
  const int c0 = (bn % 3) << 8;
  const float* bias = (which == 0) ? bq : (which == 1) ? bk : bv;

  if (which < 2) {
    u16* dst = (which == 0) ? qt : kt;
    const float mult = (which == 0) ? scaling : 1.0f;
#pragma unroll
    for (int a = 0; a < 8; ++a) {
#pragma unroll
      for (int b = 0; b < 4; ++b) {
        const int c = c0 + wn + b * 16 + coll;
        const int h = c >> 6, d = c & 63;
        const float bias_v = bias[c];
#pragma unroll
        for (int r = 0; r < 4; ++r) {
          const int m = (bm << 8) + wm + a * 16 + row4 + r;
          const int rr = m >> 9, i = m & 511;
          const float v = (acc[a][b][r] + bias_v) * mult;
          dst[((size_t)(h * 512 + i) << 13) + (rr << 6) + d] = rne_bf16(v);
        }
      }
    }
  } else {
    // v path: transpose 256x256 tile in LDS over four 64-col passes
    const int rr = bm >> 1;
    const int j0 = (bm & 1) << 8;
    const int wq4 = w & 3;                     // which pass this wave feeds
    for (int p = 0; p < 4; ++p) {
      __syncthreads();                         // prev contents consumable
      if (wq4 == p) {                          // wn == p*64
#pragma unroll
        for (int a = 0; a < 8; ++a) {
          const int ml = wm + a * 16 + row4;
#pragma unroll
          for (int b = 0; b < 4; ++b) {
            const int c = c0 + wn + b * 16 + coll;
            const int nl = b * 16 + coll;      // 0..63
            const float bias_v = bias[c];
            u16x4 pk;
#pragma unroll
            for (int r = 0; r < 4; ++r) pk[r] = rne_bf16(acc[a][b][r] + bias_v);
            *(u16x4*)(smem + nl * 264 + ml) = pk;            // Tr[64][264]
          }
        }
      }
      __syncthreads();
      for (int idx = threadIdx.x; idx < 2048; idx += 512) {
        const int nl = idx >> 5, seg = idx & 31;
        const int c = c0 + (p << 6) + nl;
        const int h = c >> 6, d = c & 63;
        u16x8 vdat = *(const u16x8*)(smem + nl * 264 + (seg << 3));
        nt_store((u16x8*)(vt2 + ((size_t)((h << 13) + (rr << 6) + d) << 9) + j0 + (seg << 3)), vdat);
      }
    }
  }
}

// ---------------------------------------------------------------------------
// Logits (128sq core): split-K by 4, partials lgp[ks][h][i][j]. grid
// (4,4,48). Partials nt-stored (read once by softmax).
// ---------------------------------------------------------------------------
__global__ __launch_bounds__(256) void k_gemm_logits(
    const u16* __restrict__ qt, const u16* __restrict__ kt,
    float* __restrict__ lgp)
{
  __shared__ __align__(16) u16 smem[32768];
  const int d0 = blockIdx.x + 4 * blockIdx.y + 16 * blockIdx.z;
  const int l  = xcd_remap(d0, 768);
  const int bm = l & 3, bn = (l >> 2) & 3;
  const int hk = l >> 4;
  const int h  = hk >> 2, ks = hk & 3;
  ACC_INIT;
  const u16* A = qt + ((size_t)h << 22) + ((size_t)bm << 20) + (ks << 11);
  const u16* B = kt + ((size_t)h << 22) + ((size_t)bn << 20) + (ks << 11);
  gemm_core(A, B, RD_, RD_, 2048, smem, acc);
  EPILOGUE_IDX;
  float* dst = lgp + ((size_t)(ks * 12 + h) << 18);
#pragma unroll
  for (int a = 0; a < 4; ++a)
#pragma unroll
    for (int b = 0; b < 4; ++b) {
      const int j = bn * 128 + wn + b * 16 + coll;
#pragma unroll
      for (int r = 0; r < 4; ++r) {
        const int i = bm * 128 + wm + a * 16 + row4 + r;
        nt_store(&dst[((size_t)i << 9) + j], acc[a][b][r]);
      }
    }
}

// ---------------------------------------------------------------------------
// Softmax over last axis, fused 4-partial sum. One block per (h,i) row.
// fp32 probs -> d_out non-temporally; bf16 pbf stays cached (re-read by ctx).
// ---------------------------------------------------------------------------
__global__ __launch_bounds__(256) void k_softmax(
    const float* __restrict__ lgp, float* __restrict__ probs,
    u16* __restrict__ pbf)
{
  const int row = blockIdx.x;                 // h*512 + i
  const size_t base = (size_t)row << 9;
  const int t = threadIdx.x;
  const int lane = t & 63, w = t >> 6;
  float x0 = (lgp[base + t]       + lgp[PART_ + base + t])
           + (lgp[2 * (size_t)PART_ + base + t]       + lgp[3 * (size_t)PART_ + base + t]);
  float x1 = (lgp[base + t + 256] + lgp[PART_ + base + t + 256])
           + (lgp[2 * (size_t)PART_ + base + t + 256] + lgp[3 * (size_t)PART_ + base + t + 256]);
  float m = fmaxf(x0, x1);
#pragma unroll
  for (int off = 32; off > 0; off >>= 1) m = fmaxf(m, __shfl_xor(m, off, 64));
  __shared__ float red[8];
  if (lane == 0) red[w] = m;
  __syncthreads();
  m = fmaxf(fmaxf(red[0], red[1]), fmaxf(red[2], red[3]));
  float e0 = __expf(x0 - m), e1 = __expf(x1 - m);
  float s = e0 + e1;
#pragma unroll
  for (int off = 32; off > 0; off >>= 1) s += __shfl_xor(s, off, 64);
  if (lane == 0) red[4 + w] = s;
  __syncthreads();
  s = (red[4] + red[5]) + (red[6] + red[7]);
  const float inv = 1.0f / s;
  const float p0 = e0 * inv, p1 = e1 * inv;
  nt_store(&probs[base + t], p0);
  nt_store(&probs[base + t + 256], p1);
  pbf[base + t]       = rne_bf16(p0);
  pbf[base + t + 256] = rne_bf16(p1);
}

// ---------------------------------------------------------------------------
// Context (256sq core): per head, probs[512x512] * vt2[h][8192x512]^T
// -> ctx[(r,i)][(h,d)]. grid (64, 12). ctx stores are 32-B partial-line
// runs -> NOT non-temporal.
// ---------------------------------------------------------------------------
__global__ __launch_bounds__(512) void k_gemm_ctx(
    const u16* __restrict__ pbf, const u16* __restrict__ vt2,
    u16* __restrict__ ctx)
{
  __shared__ __align__(16) u16 smem[65536];
  const int d0 = blockIdx.x + (blockIdx.y << 6);
  const int l  = xcd_remap(d0, 768);
  const int bm = l & 1, bn = (l >> 1) & 31, h = l >> 6;
  ACC_INIT256;
  const u16* A = pbf + ((size_t)h << 18) + ((size_t)bm << 17);
  const u16* B = vt2 + ((size_t)h << 22) + ((size_t)bn << 17);
  gemm_core256(A, B, 512, 512, 512, smem, acc);
  EPILOGUE_IDX256;
#pragma unroll
  for (int a = 0; a < 8; ++a)
#pragma unroll
    for (int b = 0; b < 4; ++b) {
      const int n = (bn << 8) + wn + b * 16 + coll;  // rd
      const int rr = n >> 6, d = n & 63;
#pragma unroll
      for (int r = 0; r < 4; ++r) {
        const int i = (bm << 8) + wm + a * 16 + row4 + r;
        ctx[(size_t)((rr << 9) + i) * E_ + (h << 6) + d] = rne_bf16(acc[a][b][r]);
      }
    }
}

// ---------------------------------------------------------------------------
// Output projection (256sq core): ctx[65536x768] * wo[768x768]^T + bo.
// grid (3, 256). out0 (200 MB fp32, never re-read) nt-stored.
// ---------------------------------------------------------------------------
__global__ __launch_bounds__(512) void k_gemm_out(
    const u16* __restrict__ ctx, const u16* __restrict__ wob,
    const float* __restrict__ bo, float* __restrict__ out0)
{
  __shared__ __align__(16) u16 smem[65536];
  const int d0 = blockIdx.x + 3 * blockIdx.y;
  const int l  = xcd_remap(d0, 768);
  const int bn = l % 3;
  const int bm = l / 3;
  ACC_INIT256;
  gemm_core256(ctx + (size_t)bm * 256 * E_, wob + (size_t)bn * 256 * E_,
               E_, E_, E_, smem, acc);
  EPILOGUE_IDX256;
#pragma unroll
  for (int a = 0; a < 8; ++a)
#pragma unroll
    for (int b = 0; b < 4; ++b) {
      const int n = (bn << 8) + wn + b * 16 + coll;
      const float bias_v = bo[n];
#pragma unroll
      for (int r = 0; r < 4; ++r) {
        const int m = (bm << 8) + wm + a * 16 + row4 + r;
        nt_store(&out0[(size_t)m * E_ + n], acc[a][b][r] + bias_v);
      }
    }
}

// ---------------------------------------------------------------------------
// fp32 -> bf16 conversion, WEIGHTS ONLY (x conversion fused into k_gemm_qkv).
// ---------------------------------------------------------------------------
__device__ __forceinline__ u16x4 cvt4(float4 v) {
  u16x4 o;
  o.x = rne_bf16(v.x); o.y = rne_bf16(v.y);
  o.z = rne_bf16(v.z); o.w = rne_bf16(v.w);
  return o;
}

__global__ __launch_bounds__(256) void k_cvt_w(
    const float4* __restrict__ wq, const float4* __restrict__ wk,
    const float4* __restrict__ wv, const float4* __restrict__ wo,
    u16x4* __restrict__ wqkv, u16x4* __restrict__ wob)
{
  const int n4 = (E_ * E_) / 4;  // 147456
  const int stride = gridDim.x * blockDim.x;
  for (int i = blockIdx.x * blockDim.x + threadIdx.x; i < n4; i += stride) {
    wqkv[i]            = cvt4(wq[i]);
    wqkv[n4 + i]       = cvt4(wk[i]);
    wqkv[2 * n4 + i]   = cvt4(wv[i]);
    wob[i]             = cvt4(wo[i]);
  }
}

__global__ void k_ws_too_small(float* out0) {
  if (threadIdx.x == 0 && blockIdx.x == 0) out0[0] = 1.0e9f;  // sentinel
}

// ---------------------------------------------------------------------------
extern "C" void kernel_launch(void* const* d_in, const int* in_sizes, int n_in,
                              void* d_out, int out_size, void* d_ws, size_t ws_size,
                              hipStream_t stream)
{
  const float* x  = (const float*)d_in[0];
  const float* wq = (const float*)d_in[1];
  const float* bq = (const float*)d_in[2];
  const float* wk = (const float*)d_in[3];
  const float* bk = (const float*)d_in[4];
  const float* wv = (const float*)d_in[5];
  const float* bv = (const float*)d_in[6];
  const float* wo = (const float*)d_in[7];
  const float* bo = (const float*)d_in[8];

  float* out0 = (float*)d_out;
  float* outp = out0 + (size_t)OUT0_N;   // probs region [12][512][512]

  // workspace layout (bytes). off 0 region: logits partials (fp32), then ctx.
  const size_t off_lgp   = 0;            // 100663296
  const size_t off_qt    = 100663296;    // 100663296
  const size_t off_kt    = 201326592;    // 100663296
  const size_t off_vt    = 301989888;    // 100663296
  const size_t off_pbf   = 402653184;    //   6291456
  const size_t off_wqkv  = 408944640;    //   3538944
  const size_t off_wob   = 412483584;    //   1179648
  const size_t need      = 413663232;

  if (ws_size < need) {
    k_ws_too_small<<<1, 64, 0, stream>>>(out0);
    return;
  }

  char* ws = (char*)d_ws;
  float* lgp = (float*)(ws + off_lgp);
  u16* ctxb = (u16*)(ws + off_lgp);      // ctx reuses the lgp region
  u16* qt   = (u16*)(ws + off_qt);
  u16* kt   = (u16*)(ws + off_kt);
  u16* vt2  = (u16*)(ws + off_vt);
  u16* pbf  = (u16*)(ws + off_pbf);
  u16* wqkv = (u16*)(ws + off_wqkv);
  u16* wob  = (u16*)(ws + off_wob);

  const float scaling = 0.011048543456039806f;  // (64^-0.5)/sqrt(128)

  k_cvt_w<<<192, 256, 0, stream>>>((const float4*)wq, (const float4*)wk,
                                   (const float4*)wv, (const float4*)wo,
                                   (u16x4*)wqkv, (u16x4*)wob);
  k_gemm_qkv<<<dim3(9, 256), 512, 0, stream>>>(x, wqkv, bq, bk, bv,
                                               qt, kt, vt2, scaling);
  k_gemm_logits<<<dim3(4, 4, 48), 256, 0, stream>>>(qt, kt, lgp);
  k_softmax<<<6144, 256, 0, stream>>>(lgp, outp, pbf);
  k_gemm_ctx<<<dim3(64, 12), 512, 0, stream>>>(pbf, vt2, ctxb);
  k_gemm_out<<<dim3(3, 256), 512, 0, stream>>>(ctxb, wob, bo, out0);
}

// Round 15
// 581.079 us; speedup vs baseline: 1.1769x; 1.1769x over previous
//
#include <hip/hip_runtime.h>
#include <hip/hip_bf16.h>

typedef unsigned short u16;
typedef u16   u16x4 __attribute__((ext_vector_type(4)));
typedef u16   u16x8 __attribute__((ext_vector_type(8)));
typedef short bf16x8 __attribute__((ext_vector_type(8)));
typedef float f32x4 __attribute__((ext_vector_type(4)));

#define R_    128
#define L_    512
#define E_    768
#define H_    12
#define RD_   8192        // R_ * 64
#define M_    65536       // R_ * L_
#define OUT0_N 50331648   // M_ * E_
#define PART_ 3145728     // 12*512*512 (one logits partial, fp32 elems)

// round-to-nearest-even fp32 -> bf16 (data has no NaN/Inf)
__device__ __forceinline__ u16 rne_bf16(float f) {
  unsigned u = __builtin_bit_cast(unsigned, f);
  u += 0x7FFFu + ((u >> 16) & 1u);
  return (u16)(u >> 16);
}

// non-temporal store: keep streaming outputs from evicting the L2 operand
// window (R13: confirmed -20us). Full-line no-reuse streams only.
// R14 lesson: do NOT fuse x->bf16 into QKV A-staging (reg-staged cvt+ds_write
// on the phase critical path = 290->462us); the standalone cvt pass is cheaper.
template <typename T>
__device__ __forceinline__ void nt_store(T* p, T v) {
  __builtin_nontemporal_store(v, p);
}

// async global->LDS, 16 B per lane (global_load_lds_dwordx4)
__device__ __forceinline__ void gload_lds16(const u16* g, u16* l) {
  __builtin_amdgcn_global_load_lds(
      (const __attribute__((address_space(1))) void*)g,
      (__attribute__((address_space(3))) void*)l, 16, 0, 0);
}

// bijective XCD-aware remap (nwg % 8 == 0): contiguous logical chunk per XCD
__device__ __forceinline__ int xcd_remap(int d, int nwg) {
  return (d & 7) * (nwg >> 3) + (d >> 3);
}

// ===========================================================================
// 256x256-tile NT GEMM core, m201-style 4-phase/K-step schedule, BK=64
// (R8 configuration -- measured session-best: QKV 285us, MfmaUtil 35%).
// 512 threads = 8 waves (2M x 4N), wave tile 128x64 via 8x4 frags of
// 16x16x32 MFMA. LDS = 2 buf x (A[256][64]+B[256][64]) = 128 KB.
// Per K-step, 4 phases (kk in {0,1} x a-half in {0,1}), each:
//   { ds_read 8 or 4 b128  ||  2 gload_lds of NEXT tile } -> s_barrier ->
//   setprio(1) 16 MFMA setprio(0) -> [counted vmcnt] -> s_barrier
// Stage order for tile t+1: B0,B1 | B2,B3 | A0,A2 | A1,A3.
// Counted waits (never drains mid-loop): end-p0 vmcnt(2) retires A1,A3 of
// CURRENT tile; end-p3 vmcnt(2) retires B0-3,A0,A2 of NEXT tile.
// Structure map (R4..R14): 64x64 wave tile -> LDS amplification 2x, worse;
// 32x32 MFMA -> inherent 4-way bank conflict; 2-buf drain-0 -> loses
// pipelining; fused fp32-A cvt -> serializes staging. This is the Pareto pt.
// Swizzle (both-sides, rule #21): L[row][s] = G[row][s ^ (row&7)].
// ===========================================================================
__device__ __forceinline__ void gemm_core256(
    const u16* __restrict__ Ab, const u16* __restrict__ Bb,
    const int lda, const int ldb, const int K,
    u16* sm, f32x4 acc[8][4])
{
  const int t    = threadIdx.x;          // 0..511
  const int lane = t & 63;
  const int w    = t >> 6;               // 0..7
  const int wm   = (w >> 2) << 7;        // 0 | 128
  const int wn   = (w & 3) << 6;         // 0..192
  const int frow = lane & 15;

  // staging: one gload covers 64 rows x 128 B (512 thr x 16 B)
  const int crow  = t >> 3;                        // row within 64-row chunk
  const int gslot = (t & 7) ^ (crow & 7);          // pre-swizzled source slot
  const u16* gA = Ab + (size_t)crow * lda + (gslot << 3);
  const u16* gB = Bb + (size_t)crow * ldb + (gslot << 3);
  const int stg = t << 3;                          // linear LDS dest (elems)

  // swizzled read slots (8 slots/row of 128 B): slot = (kk*4+(lane>>4)) ^ (lane&7)
  const int rd0 = (((lane >> 4)    ) ^ (lane & 7)) << 3;
  const int rd1 = (((lane >> 4) | 4) ^ (lane & 7)) << 3;

#define STG_A(c_, buf_, ko_) \
  gload_lds16(gA + (ko_) + (size_t)((c_) << 6) * lda, (buf_) + ((c_) << 12) + stg)
#define STG_B(c_, buf_, ko_) \
  gload_lds16(gB + (ko_) + (size_t)((c_) << 6) * ldb, (buf_) + 16384 + ((c_) << 12) + stg)

  const int nt = K >> 6;
  // prologue: tile 0, issue order B0,B1,B2,B3,A0,A2,A1,A3
  STG_B(0, sm, 0); STG_B(1, sm, 0); STG_B(2, sm, 0); STG_B(3, sm, 0);
  STG_A(0, sm, 0); STG_A(2, sm, 0); STG_A(1, sm, 0); STG_A(3, sm, 0);
  asm volatile("s_waitcnt vmcnt(2)" ::: "memory");   // all but A1,A3 landed
  __builtin_amdgcn_s_barrier();

  for (int tt = 0; tt < nt; ++tt) {
    u16* bufc = sm + ((tt & 1) << 15);
    u16* bufn = sm + (((tt + 1) & 1) << 15);
    const bool st = (tt + 1 < nt);
    const int ko = (tt + 1) << 6;

    bf16x8 af[4], bff[4];
    // ---------- phase 0: kk=0, a=0..3 ; stage B0,B1 of t+1 ----------
#pragma unroll
    for (int b = 0; b < 4; ++b)
      bff[b] = *(const bf16x8*)(bufc + 16384 + ((wn + b * 16 + frow) << 6) + rd0);
#pragma unroll
    for (int a = 0; a < 4; ++a)
      af[a] = *(const bf16x8*)(bufc + ((wm + a * 16 + frow) << 6) + rd0);
    if (st) { STG_B(0, bufn, ko); STG_B(1, bufn, ko); }
    __builtin_amdgcn_s_barrier();
    __builtin_amdgcn_s_setprio(1);
#pragma unroll
    for (int a = 0; a < 4; ++a)
#pragma unroll
      for (int b = 0; b < 4; ++b)
        acc[a][b] = __builtin_amdgcn_mfma_f32_16x16x32_bf16(af[a], bff[b], acc[a][b], 0, 0, 0);
    __builtin_amdgcn_s_setprio(0);
    if (st) asm volatile("s_waitcnt vmcnt(2)" ::: "memory");  // A1,A3 of cur landed
    else    asm volatile("s_waitcnt vmcnt(0)" ::: "memory");
    __builtin_amdgcn_s_barrier();

    // ---------- phase 1: kk=0, a=4..7 ; stage B2,B3 of t+1 ----------
#pragma unroll
    for (int a = 0; a < 4; ++a)
      af[a] = *(const bf16x8*)(bufc + ((wm + (a + 4) * 16 + frow) << 6) + rd0);
    if (st) { STG_B(2, bufn, ko); STG_B(3, bufn, ko); }
    __builtin_amdgcn_s_barrier();
    __builtin_amdgcn_s_setprio(1);
#pragma unroll
    for (int a = 0; a < 4; ++a)
#pragma unroll
      for (int b = 0; b < 4; ++b)
        acc[a + 4][b] = __builtin_amdgcn_mfma_f32_16x16x32_bf16(af[a], bff[b], acc[a + 4][b], 0, 0, 0);
    __builtin_amdgcn_s_setprio(0);
    __builtin_amdgcn_s_barrier();

    // ---------- phase 2: kk=1, a=0..3 ; stage A0,A2 of t+1 ----------
#pragma unroll
    for (int b = 0; b < 4; ++b)
      bff[b] = *(const bf16x8*)(bufc + 16384 + ((wn + b * 16 + frow) << 6) + rd1);
#pragma unroll
    for (int a = 0; a < 4; ++a)
      af[a] = *(const bf16x8*)(bufc + ((wm + a * 16 + frow) << 6) + rd1);
    if (st) { STG_A(0, bufn, ko); STG_A(2, bufn, ko); }
    __builtin_amdgcn_s_barrier();
    __builtin_amdgcn_s_setprio(1);
#pragma unroll
    for (int a = 0; a < 4; ++a)
#pragma unroll
      for (int b = 0; b < 4; ++b)
        acc[a][b] = __builtin_amdgcn_mfma_f32_16x16x32_bf16(af[a], bff[b], acc[a][b], 0, 0, 0);
    __builtin_amdgcn_s_setprio(0);
    __builtin_amdgcn_s_barrier();

    // ---------- phase 3: kk=1, a=4..7 ; stage A1,A3 of t+1 ----------
#pragma unroll
    for (int a = 0; a < 4; ++a)
      af[a] = *(const bf16x8*)(bufc + ((wm + (a + 4) * 16 + frow) << 6) + rd1);
    if (st) { STG_A(1, bufn, ko); STG_A(3, bufn, ko); }
    __builtin_amdgcn_s_barrier();
    __builtin_amdgcn_s_setprio(1);
#pragma unroll
    for (int a = 0; a < 4; ++a)
#pragma unroll
      for (int b = 0; b < 4; ++b)
        acc[a + 4][b] = __builtin_amdgcn_mfma_f32_16x16x32_bf16(af[a], bff[b], acc[a + 4][b], 0, 0, 0);
    __builtin_amdgcn_s_setprio(0);
    if (st) asm volatile("s_waitcnt vmcnt(2)" ::: "memory");  // B0-3,A0,A2 of t+1 landed
    __builtin_amdgcn_s_barrier();
  }
#undef STG_A
#undef STG_B
}

#define EPILOGUE_IDX256                           \
  const int lane = threadIdx.x & 63;              \
  const int w    = threadIdx.x >> 6;              \
  const int wm   = (w >> 2) << 7;                 \
  const int wn   = (w & 3) << 6;                  \
  const int row4 = (lane >> 4) << 2;              \
  const int coll = lane & 15;

#define ACC_INIT256                               \
  f32x4 acc[8][4];                                \
  {                                               \
    f32x4 zz = {0.0f, 0.0f, 0.0f, 0.0f};          \
    _Pragma("unroll")                             \
    for (int a = 0; a < 8; ++a)                   \
      _Pragma("unroll")                           \
      for (int b = 0; b < 4; ++b) acc[a][b] = zz; \
  }

// ===========================================================================
// 128x128-tile core (proven rounds 2-4) -- kept for k_gemm_logits.
// ===========================================================================
__device__ __forceinline__ void gemm_core(
    const u16* __restrict__ Ab, const u16* __restrict__ Bb,
    const int lda, const int ldb, const int K,
    u16* sm, f32x4 acc[4][4])
{
  const int t    = threadIdx.x;
  const int lane = t & 63;
  const int w    = t >> 6;
  const int wm   = (w >> 1) << 6;
  const int wn   = (w & 1) << 6;
  const int frow = lane & 15;

  const int srow = (w << 3) + (lane >> 3);
  const int scol = ((lane & 7) ^ (lane >> 3)) << 3;   // swizzled global col
  const u16* gA = Ab + (size_t)srow * lda + scol;
  const u16* gB = Bb + (size_t)srow * ldb + scol;
  const int stg_l = (w << 9) + (lane << 3);           // linear LDS dest

#pragma unroll
  for (int j = 0; j < 4; ++j) {
    gload_lds16(gA + (size_t)(j << 5) * lda, sm + (j << 11) + stg_l);
    gload_lds16(gB + (size_t)(j << 5) * ldb, sm + 8192 + (j << 11) + stg_l);
  }

  const int nt = K >> 6;
  for (int tt = 0; tt < nt; ++tt) {
    const int cur = tt & 1;
    u16* bufc = sm + (cur << 14);
    u16* bufn = sm + ((cur ^ 1) << 14);
    __builtin_amdgcn_s_barrier();
    if (tt + 1 < nt) {
      const u16* gA1 = gA + ((size_t)(tt + 1) << 6);
      const u16* gB1 = gB + ((size_t)(tt + 1) << 6);
#pragma unroll
      for (int j = 0; j < 4; ++j) {
        gload_lds16(gA1 + (size_t)(j << 5) * lda, bufn + (j << 11) + stg_l);
        gload_lds16(gB1 + (size_t)(j << 5) * ldb, bufn + 8192 + (j << 11) + stg_l);
      }
      asm volatile("s_waitcnt vmcnt(8)" ::: "memory");
    } else {
      asm volatile("s_waitcnt vmcnt(0)" ::: "memory");
    }
    __builtin_amdgcn_s_barrier();
    const u16* sA = bufc;
    const u16* sB = bufc + 8192;
#pragma unroll
    for (int kk = 0; kk < 2; ++kk) {
      const int rdcol = (((kk << 2) + (lane >> 4)) ^ (lane & 7)) << 3;
      bf16x8 af[4], bff[4];
#pragma unroll
      for (int a = 0; a < 4; ++a)
        af[a] = *(const bf16x8*)(sA + ((wm + a * 16 + frow) << 6) + rdcol);
#pragma unroll
      for (int b = 0; b < 4; ++b)
        bff[b] = *(const bf16x8*)(sB + ((wn + b * 16 + frow) << 6) + rdcol);
#pragma unroll
      for (int a = 0; a < 4; ++a)
#pragma unroll
        for (int b = 0; b < 4; ++b)
          acc[a][b] = __builtin_amdgcn_mfma_f32_16x16x32_bf16(af[a], bff[b], acc[a][b], 0, 0, 0);
    }
  }
}

#define EPILOGUE_IDX                              \
  const int lane = threadIdx.x & 63;              \
  const int w    = threadIdx.x >> 6;              \
  const int wm   = (w >> 1) << 6;                 \
  const int wn   = (w & 1) << 6;                  \
  const int row4 = (lane >> 4) << 2;              \
  const int coll = lane & 15;

#define ACC_INIT                                  \
  f32x4 acc[4][4];                                \
  {                                               \
    f32x4 zz = {0.0f, 0.0f, 0.0f, 0.0f};          \
    _Pragma("unroll")                             \
    for (int a = 0; a < 4; ++a)                   \
      _Pragma("unroll")                           \
      for (int b = 0; b < 4; ++b) acc[a][b] = zz; \
  }

// ---------------------------------------------------------------------------
// QKV projection (256sq core): xbf[65536x768] @ wqkv[2304x768]^T (+bias).
// q,k -> [h][i][r*64+d]; v -> transposed [h][r*64+d][j] via 4-pass LDS Tr.
// grid (9, 256): bn fastest + XCD remap.
// ---------------------------------------------------------------------------
__global__ __launch_bounds__(512) void k_gemm_qkv(
    const u16* __restrict__ xbf, const u16* __restrict__ wqkv,
    const float* __restrict__ bq, const float* __restrict__ bk,
    const float* __restrict__ bv,
    u16* __restrict__ qt, u16* __restrict__ kt, u16* __restrict__ vt2,
    const float scaling)
{
  __shared__ __align__(16) u16 smem[65536];   // 128 KB: 2 x (A 32K | B 32K)
  const int d0 = blockIdx.x + 9 * blockIdx.y;
  const int l  = xcd_remap(d0, 2304);
  const int bn = l % 9;
  const int bm = l / 9;
  ACC_INIT256;
  gemm_core256(xbf + (size_t)bm * 256 * E_, wqkv + (size_t)bn * 256 * E_,
               E_, E_, E_, smem, acc);
  EPILOGUE_IDX256;
  const int which = bn / 3;
  const int c0 = (bn % 3) << 8;
  const float* bias = (which == 0) ? bq : (which == 1) ? bk : bv;

  if (which < 2) {
    u16* dst = (which == 0) ? qt : kt;
    const float mult = (which == 0) ? scaling : 1.0f;
#pragma unroll
    for (int a = 0; a < 8; ++a) {
#pragma unroll
      for (int b = 0; b < 4; ++b) {
        const int c = c0 + wn + b * 16 + coll;
        const int h = c >> 6, d = c & 63;
        const float bias_v = bias[c];
#pragma unroll
        for (int r = 0; r < 4; ++r) {
          const int m = (bm << 8) + wm + a * 16 + row4 + r;
          const int rr = m >> 9, i = m & 511;
          const float v = (acc[a][b][r] + bias_v) * mult;
          dst[((size_t)(h * 512 + i) << 13) + (rr << 6) + d] = rne_bf16(v);
        }
      }
    }
  } else {
    // v path: transpose 256x256 tile in LDS over four 64-col passes
    const int rr = bm >> 1;
    const int j0 = (bm & 1) << 8;
    const int wq4 = w & 3;                     // which pass this wave feeds
    for (int p = 0; p < 4; ++p) {
      __syncthreads();                         // prev contents consumable
      if (wq4 == p) {                          // wn == p*64
#pragma unroll
        for (int a = 0; a < 8; ++a) {
          const int ml = wm + a * 16 + row4;
#pragma unroll
          for (int b = 0; b < 4; ++b) {
            const int c = c0 + wn + b * 16 + coll;
            const int nl = b * 16 + coll;      // 0..63
            const float bias_v = bias[c];
            u16x4 pk;
#pragma unroll
            for (int r = 0; r < 4; ++r) pk[r] = rne_bf16(acc[a][b][r] + bias_v);
            *(u16x4*)(smem + nl * 264 + ml) = pk;            // Tr[64][264]
          }
        }
      }
      __syncthreads();
      for (int idx = threadIdx.x; idx < 2048; idx += 512) {
        const int nl = idx >> 5, seg = idx & 31;
        const int c = c0 + (p << 6) + nl;
        const int h = c >> 6, d = c & 63;
        u16x8 vdat = *(const u16x8*)(smem + nl * 264 + (seg << 3));
        nt_store((u16x8*)(vt2 + ((size_t)((h << 13) + (rr << 6) + d) << 9) + j0 + (seg << 3)), vdat);
      }
    }
  }
}

// ---------------------------------------------------------------------------
// Logits (128sq core): split-K by 4, partials lgp[ks][h][i][j]. grid
// (4,4,48). Partials nt-stored (read once by softmax).
// ---------------------------------------------------------------------------
__global__ __launch_bounds__(256) void k_gemm_logits(
    const u16* __restrict__ qt, const u16* __restrict__ kt,
    float* __restrict__ lgp)
{
  __shared__ __align__(16) u16 smem[32768];
  const int d0 = blockIdx.x + 4 * blockIdx.y + 16 * blockIdx.z;
  const int l  = xcd_remap(d0, 768);
  const int bm = l & 3, bn = (l >> 2) & 3;
  const int hk = l >> 4;
  const int h  = hk >> 2, ks = hk & 3;
  ACC_INIT;
  const u16* A = qt + ((size_t)h << 22) + ((size_t)bm << 20) + (ks << 11);
  const u16* B = kt + ((size_t)h << 22) + ((size_t)bn << 20) + (ks << 11);
  gemm_core(A, B, RD_, RD_, 2048, smem, acc);
  EPILOGUE_IDX;
  float* dst = lgp + ((size_t)(ks * 12 + h) << 18);
#pragma unroll
  for (int a = 0; a < 4; ++a)
#pragma unroll
    for (int b = 0; b < 4; ++b) {
      const int j = bn * 128 + wn + b * 16 + coll;
#pragma unroll
      for (int r = 0; r < 4; ++r) {
        const int i = bm * 128 + wm + a * 16 + row4 + r;
        nt_store(&dst[((size_t)i << 9) + j], acc[a][b][r]);
      }
    }
}

// ---------------------------------------------------------------------------
// Softmax over last axis, fused 4-partial sum. One block per (h,i) row.
// fp32 probs -> d_out non-temporally; bf16 pbf stays cached (re-read by ctx).
// ---------------------------------------------------------------------------
__global__ __launch_bounds__(256) void k_softmax(
    const float* __restrict__ lgp, float* __restrict__ probs,
    u16* __restrict__ pbf)
{
  const int row = blockIdx.x;                 // h*512 + i
  const size_t base = (size_t)row << 9;
  const int t = threadIdx.x;
  const int lane = t & 63, w = t >> 6;
  float x0 = (lgp[base + t]       + lgp[PART_ + base + t])
           + (lgp[2 * (size_t)PART_ + base + t]       + lgp[3 * (size_t)PART_ + base + t]);
  float x1 = (lgp[base + t + 256] + lgp[PART_ + base + t + 256])
           + (lgp[2 * (size_t)PART_ + base + t + 256] + lgp[3 * (size_t)PART_ + base + t + 256]);
  float m = fmaxf(x0, x1);
#pragma unroll
  for (int off = 32; off > 0; off >>= 1) m = fmaxf(m, __shfl_xor(m, off, 64));
  __shared__ float red[8];
  if (lane == 0) red[w] = m;
  __syncthreads();
  m = fmaxf(fmaxf(red[0], red[1]), fmaxf(red[2], red[3]));
  float e0 = __expf(x0 - m), e1 = __expf(x1 - m);
  float s = e0 + e1;
#pragma unroll
  for (int off = 32; off > 0; off >>= 1) s += __shfl_xor(s, off, 64);
  if (lane == 0) red[4 + w] = s;
  __syncthreads();
  s = (red[4] + red[5]) + (red[6] + red[7]);
  const float inv = 1.0f / s;
  const float p0 = e0 * inv, p1 = e1 * inv;
  nt_store(&probs[base + t], p0);
  nt_store(&probs[base + t + 256], p1);
  pbf[base + t]       = rne_bf16(p0);
  pbf[base + t + 256] = rne_bf16(p1);
}

// ---------------------------------------------------------------------------
// Context (256sq core): per head, probs[512x512] * vt2[h][8192x512]^T
// -> ctx[(r,i)][(h,d)]. grid (64, 12). ctx stores are 32-B partial-line
// runs -> NOT non-temporal.
// ---------------------------------------------------------------------------
__global__ __launch_bounds__(512) void k_gemm_ctx(
    const u16* __restrict__ pbf, const u16* __restrict__ vt2,
    u16* __restrict__ ctx)
{
  __shared__ __align__(16) u16 smem[65536];
  const int d0 = blockIdx.x + (blockIdx.y << 6);
  const int l  = xcd_remap(d0, 768);
  const int bm = l & 1, bn = (l >> 1) & 31, h = l >> 6;
  ACC_INIT256;
  const u16* A = pbf + ((size_t)h << 18) + ((size_t)bm << 17);
  const u16* B = vt2 + ((size_t)h << 22) + ((size_t)bn << 17);
  gemm_core256(A, B, 512, 512, 512, smem, acc);
  EPILOGUE_IDX256;
#pragma unroll
  for (int a = 0; a < 8; ++a)
#pragma unroll
    for (int b = 0; b < 4; ++b) {
      const int n = (bn << 8) + wn + b * 16 + coll;  // rd
      const int rr = n >> 6, d = n & 63;
#pragma unroll
      for (int r = 0; r < 4; ++r) {
        const int i = (bm << 8) + wm + a * 16 + row4 + r;
        ctx[(size_t)((rr << 9) + i) * E_ + (h << 6) + d] = rne_bf16(acc[a][b][r]);
      }
    }
}

// ---------------------------------------------------------------------------
// Output projection (256sq core): ctx[65536x768] * wo[768x768]^T + bo.
// grid (3, 256). out0 (200 MB fp32, never re-read) nt-stored.
// ---------------------------------------------------------------------------
__global__ __launch_bounds__(512) void k_gemm_out(
    const u16* __restrict__ ctx, const u16* __restrict__ wob,
    const float* __restrict__ bo, float* __restrict__ out0)
{
  __shared__ __align__(16) u16 smem[65536];
  const int d0 = blockIdx.x + 3 * blockIdx.y;
  const int l  = xcd_remap(d0, 768);
  const int bn = l % 3;
  const int bm = l / 3;
  ACC_INIT256;
  gemm_core256(ctx + (size_t)bm * 256 * E_, wob + (size_t)bn * 256 * E_,
               E_, E_, E_, smem, acc);
  EPILOGUE_IDX256;
#pragma unroll
  for (int a = 0; a < 8; ++a)
#pragma unroll
    for (int b = 0; b < 4; ++b) {
      const int n = (bn << 8) + wn + b * 16 + coll;
      const float bias_v = bo[n];
#pragma unroll
      for (int r = 0; r < 4; ++r) {
        const int m = (bm << 8) + wm + a * 16 + row4 + r;
        nt_store(&out0[(size_t)m * E_ + n], acc[a][b][r] + bias_v);
      }
    }
}

// ---------------------------------------------------------------------------
// fp32 -> bf16 conversions (x + all four weight matrices in one launch).
// xbf (100 MB stream) non-temporal; wqkv/wob kept cached (re-read by GEMMs).
// ---------------------------------------------------------------------------
__device__ __forceinline__ u16x4 cvt4(float4 v) {
  u16x4 o;
  o.x = rne_bf16(v.x); o.y = rne_bf16(v.y);
  o.z = rne_bf16(v.z); o.w = rne_bf16(v.w);
  return o;
}

__global__ __launch_bounds__(256) void k_cvt_all(
    const float4* __restrict__ x,
    const float4* __restrict__ wq, const float4* __restrict__ wk,
    const float4* __restrict__ wv, const float4* __restrict__ wo,
    u16x4* __restrict__ xbf, u16x4* __restrict__ wqkv, u16x4* __restrict__ wob)
{
  const int n4x = OUT0_N / 4;      // 12582912
  const int n4w = (E_ * E_) / 4;   // 147456
  const int stride = gridDim.x * blockDim.x;
  for (int i = blockIdx.x * blockDim.x + threadIdx.x; i < n4x; i += stride) {
    nt_store(&xbf[i], cvt4(x[i]));
    if (i < n4w) {
      wqkv[i]          = cvt4(wq[i]);
      wqkv[n4w + i]    = cvt4(wk[i]);
      wqkv[2 * n4w + i] = cvt4(wv[i]);
      wob[i]           = cvt4(wo[i]);
    }
  }
}

__global__ void k_ws_too_small(float* out0) {
  if (threadIdx.x == 0 && blockIdx.x == 0) out0[0] = 1.0e9f;  // sentinel
}

// ---------------------------------------------------------------------------
extern "C" void kernel_launch(void* const* d_in, const int* in_sizes, int n_in,
                              void* d_out, int out_size, void* d_ws, size_t ws_size,
                              hipStream_t stream)
{
  const float* x  = (const float*)d_in[0];
  const float* wq = (const float*)d_in[1];
  const float* bq = (const float*)d_in[2];
  const float* wk = (const float*)d_in[3];
  const float* bk = (const float*)d_in[4];
  const float* wv = (const float*)d_in[5];
  const float* bv = (const float*)d_in[6];
  const float* wo = (const float*)d_in[7];
  const float* bo = (const float*)d_in[8];

  float* out0 = (float*)d_out;
  float* outp = out0 + (size_t)OUT0_N;   // probs region [12][512][512]

  // workspace layout (bytes)
  const size_t off_xbf   = 0;            // 100663296 (x bf16; then logits partials; then ctx)
  const size_t off_qt    = 100663296;    // 100663296
  const size_t off_kt    = 201326592;    // 100663296
  const size_t off_vt    = 301989888;    // 100663296
  const size_t off_pbf   = 402653184;    //   6291456
  const size_t off_wqkv  = 408944640;    //   3538944
  const size_t off_wob   = 412483584;    //   1179648
  const size_t need      = 413663232;

  if (ws_size < need) {
    k_ws_too_small<<<1, 64, 0, stream>>>(out0);
    return;
  }

  char* ws = (char*)d_ws;
  u16* xbf  = (u16*)(ws + off_xbf);      // reused: logits partials (fp32), then ctx
  float* lgp = (float*)(ws + off_xbf);
  u16* qt   = (u16*)(ws + off_qt);
  u16* kt   = (u16*)(ws + off_kt);
  u16* vt2  = (u16*)(ws + off_vt);
  u16* pbf  = (u16*)(ws + off_pbf);
  u16* wqkv = (u16*)(ws + off_wqkv);
  u16* wob  = (u16*)(ws + off_wob);

  const float scaling = 0.011048543456039806f;  // (64^-0.5)/sqrt(128)

  k_cvt_all<<<2048, 256, 0, stream>>>((const float4*)x,
                                      (const float4*)wq, (const float4*)wk,
                                      (const float4*)wv, (const float4*)wo,
                                      (u16x4*)xbf, (u16x4*)wqkv, (u16x4*)wob);
  k_gemm_qkv<<<dim3(9, 256), 512, 0, stream>>>(xbf, wqkv, bq, bk, bv,
                                               qt, kt, vt2, scaling);
  k_gemm_logits<<<dim3(4, 4, 48), 256, 0, stream>>>(qt, kt, lgp);
  k_softmax<<<6144, 256, 0, stream>>>(lgp, outp, pbf);
  k_gemm_ctx<<<dim3(64, 12), 512, 0, stream>>>(pbf, vt2, xbf /*ctx*/);
  k_gemm_out<<<dim3(3, 256), 512, 0, stream>>>(xbf, wob, bo, out0);
}